// Round 3
// baseline (2346.737 us; speedup 1.0000x reference)
//
#include <hip/hip_runtime.h>
#include <math.h>

#define NB   256
#define LSEQ 1800
#define NF   50
#define NE   4
#define NH   32
#define G3   96
#define ND   64
#define NHU  32
#define CHUNK 60
#define TBLK  12
#define NCHUNK (LSEQ / CHUNK)   // 30
#define NBLK   (CHUNK / TBLK)   // 5

// ---------------------------------------------------------------------------
// Kernel 1: fold input projection into layer-0 input weights.
// C[e][f][g] = sum_d Wih0[e][g][d] * W_in[d][f]   (stored f-major for LDS copy)
// ---------------------------------------------------------------------------
__global__ void compute_C_kernel(const float* __restrict__ Wih0,
                                 const float* __restrict__ W_in,
                                 float* __restrict__ Cg) {
    int e = blockIdx.x;
    for (int idx = threadIdx.x; idx < NF * G3; idx += blockDim.x) {
        int f = idx / G3;
        int g = idx - f * G3;
        const float* wr = Wih0 + ((size_t)e * G3 + g) * ND;
        float s = 0.f;
        #pragma unroll 8
        for (int d = 0; d < ND; d++) s += wr[d] * W_in[d * NF + f];
        Cg[(size_t)e * NF * G3 + idx] = s;
    }
}

// Fast transcendentals on v_exp_f32 / v_rcp_f32.
__device__ __forceinline__ float fsig(float x) {
    float e = __builtin_amdgcn_exp2f(-1.442695041f * x);
    return __builtin_amdgcn_rcpf(1.f + e);
}
__device__ __forceinline__ float ftanh(float x) {
    x = fmaxf(x, -20.f);
    float e = __builtin_amdgcn_exp2f(-2.885390082f * x);
    return (1.f - e) * __builtin_amdgcn_rcpf(1.f + e);
}

// ---------------------------------------------------------------------------
// One 64-thread (single-wave) block per (batch, expert); unrouted blocks exit.
// Lane (j = tid&31, hlf = tid>>5) owns gate rows {j, j+32, j+64}, k-half
// [16*hlf, 16*hlf+16). Software pipeline with 1-step skew: iteration t
// computes L0(t) in parallel with L1(t-1), so both layers share ONE shfl-
// reduce latency stage and ONE broadcast stage per step. h state exchanged
// via ds_bpermute (__shfl) only — no LDS in the loop, no barriers (single
// wave => DS ops in order).
// ---------------------------------------------------------------------------
__global__ __launch_bounds__(64, 1)
void moe_gru_kernel(const float* __restrict__ x,
                    const int*   __restrict__ horizon,
                    const float* __restrict__ emb,
                    const float* __restrict__ W_gate,
                    const float* __restrict__ b_gate,
                    const float* __restrict__ b_in,
                    const float* __restrict__ Wih0,
                    const float* __restrict__ Whh0,
                    const float* __restrict__ bih0,
                    const float* __restrict__ bhh0,
                    const float* __restrict__ Wih1,
                    const float* __restrict__ Whh1,
                    const float* __restrict__ bih1,
                    const float* __restrict__ bhh1,
                    const float* __restrict__ Wh1,
                    const float* __restrict__ bh1,
                    const float* __restrict__ Wh2,
                    const float* __restrict__ bh2,
                    const float* __restrict__ Cg,
                    float* __restrict__ out) {
    __shared__ __align__(16) float smem[4800 + 3008 + 64 + 64 + 32];
    float* CT  = smem;                  // [f][96]  folded input weights
    float* xs  = smem + 4800;           // [f][CHUNK] transposed x chunk
    float* heL = smem + 4800 + 3008;    // 64: h_embed
    float* bbL = heL + 64;              // 64: b_in + h_embed
    float* h1L = bbL + 64;              // 32: final h1 for head

    const int bid = blockIdx.x;
    const int b   = bid >> 2;
    const int e   = bid & 3;
    const int tid = threadIdx.x;
    const int j   = tid & 31;
    const int hlf = tid >> 5;
    const int k0  = hlf << 4;

    // ---- stage h_embed / (b_in + h_embed) (wave-synchronous) ----
    {
        int hor = horizon[b];
        float he = emb[(size_t)hor * ND + tid];
        heL[tid] = he;
        bbL[tid] = he + b_in[tid];
    }

    // ---- gating (every thread computes identically) ----
    float lg[NE];
    #pragma unroll
    for (int q = 0; q < NE; q++) {
        float s = b_gate[q];
        for (int d = 0; d < ND; d++) s += heL[d] * W_gate[q * ND + d];
        lg[q] = s;
    }
    int i1 = 0;
    #pragma unroll
    for (int q = 1; q < NE; q++) if (lg[q] > lg[i1]) i1 = q;
    int i2 = (i1 == 0) ? 1 : 0;
    #pragma unroll
    for (int q = 0; q < NE; q++) if (q != i1 && lg[q] > lg[i2]) i2 = q;
    if (e != i1 && e != i2) return;          // block-uniform
    const float ex2 = expf(lg[i2] - lg[i1]);
    const float wgt = (e == i1) ? (1.f / (1.f + ex2)) : (ex2 / (1.f + ex2));

    // ---- stage folded input weights for this expert ----
    for (int idx = tid; idx < NF * G3; idx += 64)
        CT[idx] = Cg[(size_t)e * NF * G3 + idx];

    // ---- per-thread register weights: rows {j, j+32, j+64}, k in [k0,k0+16) ----
    float wh0[3][16], wi1[3][16], wh1[3][16];
    float bhh0r[3], bih1r[3], bhh1r[3], dreg[3];
    #pragma unroll
    for (int c = 0; c < 3; c++) {
        const int row = j + 32 * c;
        {
            const float4* p = (const float4*)(Whh0 + ((size_t)e * G3 + row) * NH + k0);
            float4 A0 = p[0], A1 = p[1], A2 = p[2], A3 = p[3];
            wh0[c][0]=A0.x; wh0[c][1]=A0.y; wh0[c][2]=A0.z; wh0[c][3]=A0.w;
            wh0[c][4]=A1.x; wh0[c][5]=A1.y; wh0[c][6]=A1.z; wh0[c][7]=A1.w;
            wh0[c][8]=A2.x; wh0[c][9]=A2.y; wh0[c][10]=A2.z; wh0[c][11]=A2.w;
            wh0[c][12]=A3.x; wh0[c][13]=A3.y; wh0[c][14]=A3.z; wh0[c][15]=A3.w;
        }
        {
            const float4* p = (const float4*)(Wih1 + ((size_t)e * G3 + row) * NH + k0);
            float4 A0 = p[0], A1 = p[1], A2 = p[2], A3 = p[3];
            wi1[c][0]=A0.x; wi1[c][1]=A0.y; wi1[c][2]=A0.z; wi1[c][3]=A0.w;
            wi1[c][4]=A1.x; wi1[c][5]=A1.y; wi1[c][6]=A1.z; wi1[c][7]=A1.w;
            wi1[c][8]=A2.x; wi1[c][9]=A2.y; wi1[c][10]=A2.z; wi1[c][11]=A2.w;
            wi1[c][12]=A3.x; wi1[c][13]=A3.y; wi1[c][14]=A3.z; wi1[c][15]=A3.w;
        }
        {
            const float4* p = (const float4*)(Whh1 + ((size_t)e * G3 + row) * NH + k0);
            float4 A0 = p[0], A1 = p[1], A2 = p[2], A3 = p[3];
            wh1[c][0]=A0.x; wh1[c][1]=A0.y; wh1[c][2]=A0.z; wh1[c][3]=A0.w;
            wh1[c][4]=A1.x; wh1[c][5]=A1.y; wh1[c][6]=A1.z; wh1[c][7]=A1.w;
            wh1[c][8]=A2.x; wh1[c][9]=A2.y; wh1[c][10]=A2.z; wh1[c][11]=A2.w;
            wh1[c][12]=A3.x; wh1[c][13]=A3.y; wh1[c][14]=A3.z; wh1[c][15]=A3.w;
        }
        bhh0r[c] = bhh0[e * G3 + row];
        bih1r[c] = bih1[e * G3 + row];
        bhh1r[c] = bhh1[e * G3 + row];
        // dvec = bih0 + Wih0 @ (b_in + h_embed); added only by half 0
        float s = bih0[e * G3 + row];
        const float* wr = Wih0 + ((size_t)e * G3 + row) * ND;
        for (int d = 0; d < ND; d++) s += wr[d] * bbL[d];
        dreg[c] = hlf ? 0.f : s;
    }

    // ---- pipeline state ----
    float h0r[16], h1r[16];
    #pragma unroll
    for (int k = 0; k < 16; k++) { h0r[k] = 0.f; h1r[k] = 0.f; }
    float h0old = 0.f, h1old = 0.f;
    float xq0 = 0.f, xq1 = 0.f, xq2 = 0.f;   // wi1 . h0[t-1] partials (pre-shfl)
    float l1gate = 0.f;                      // 0 only on the very first iteration

    const float* xg = x + (size_t)b * LSEQ * NF;

    for (int ch = 0; ch < NCHUNK; ch++) {
        // stage x chunk (contiguous float4 global loads), transpose to [f][t]
        {
            const float4* xc4 = (const float4*)(xg + (size_t)ch * CHUNK * NF);
            for (int i4 = tid; i4 < (CHUNK * NF) / 4; i4 += 64) {
                float4 v = xc4[i4];
                int idx = i4 * 4;
                #pragma unroll
                for (int u = 0; u < 4; u++) {
                    int id = idx + u;
                    int it = (int)(((unsigned)id * 5243u) >> 18);   // id/50
                    int f  = id - it * 50;
                    float val = (u == 0) ? v.x : (u == 1) ? v.y : (u == 2) ? v.z : v.w;
                    xs[f * CHUNK + it] = val;
                }
            }
        }

        for (int blk = 0; blk < NBLK; blk++) {
            const int ib0 = blk * TBLK;
            // ---- xg0 partial (this half's 25 features) for TBLK steps ----
            float acc0[TBLK], acc1[TBLK], acc2[TBLK];
            #pragma unroll
            for (int i = 0; i < TBLK; i++) {
                acc0[i] = dreg[0]; acc1[i] = dreg[1]; acc2[i] = dreg[2];
            }
            #pragma unroll 5
            for (int f = 0; f < 25; f++) {
                const int fg = f + 25 * hlf;
                float c0 = CT[fg * G3 + j];
                float c1 = CT[fg * G3 + j + 32];
                float c2 = CT[fg * G3 + j + 64];
                const float4* xp = (const float4*)(xs + fg * CHUNK + ib0);
                float4 xa = xp[0], xb = xp[1], xc4 = xp[2];
                float xv[TBLK] = {xa.x, xa.y, xa.z, xa.w,
                                  xb.x, xb.y, xb.z, xb.w,
                                  xc4.x, xc4.y, xc4.z, xc4.w};
                #pragma unroll
                for (int i = 0; i < TBLK; i++) {
                    acc0[i] += c0 * xv[i];
                    acc1[i] += c1 * xv[i];
                    acc2[i] += c2 * xv[i];
                }
            }

            // ---- TBLK pipelined steps: L0(t) || L1(t-1) ----
            #pragma unroll
            for (int i = 0; i < TBLK; i++) {
                // L0 dots: gh0 on h0r (= h0[t-1])
                float p0 = hlf ? 0.f : bhh0r[0];
                float p1 = hlf ? 0.f : bhh0r[1];
                float p2 = hlf ? 0.f : bhh0r[2];
                // L1 dots: gh1 on h1r (= h1[t-2]) — independent
                float g0 = hlf ? 0.f : bhh1r[0];
                float g1 = hlf ? 0.f : bhh1r[1];
                float g2 = hlf ? 0.f : bhh1r[2];
                #pragma unroll
                for (int k = 0; k < 16; k++) {
                    p0 += wh0[0][k] * h0r[k];
                    p1 += wh0[1][k] * h0r[k];
                    p2 += wh0[2][k] * h0r[k];
                    g0 += wh1[0][k] * h1r[k];
                    g1 += wh1[1][k] * h1r[k];
                    g2 += wh1[2][k] * h1r[k];
                }
                // ---- stage A: all 8 half-sum shfls in one latency stage ----
                float sr  = acc0[i] + p0;  sr  += __shfl_xor(sr, 32, 64);
                float sz  = acc1[i] + p1;  sz  += __shfl_xor(sz, 32, 64);
                float xn  = acc2[i];       xn  += __shfl_xor(xn, 32, 64);
                float gn  = p2;            gn  += __shfl_xor(gn, 32, 64);
                float s1r = xq0 + g0;      s1r += __shfl_xor(s1r, 32, 64);
                float s1z = xq1 + g1;      s1z += __shfl_xor(s1z, 32, 64);
                float xn1 = xq2;           xn1 += __shfl_xor(xn1, 32, 64);
                float gn1 = g2;            gn1 += __shfl_xor(gn1, 32, 64);
                // ---- transcendentals: both layers in parallel ----
                float r  = fsig(sr);
                float z  = fsig(sz);
                float n  = ftanh(xn + r * gn);
                float h0new = n + z * (h0old - n);
                h0old = h0new;
                float r1 = fsig(s1r);
                float z1 = fsig(s1z);
                float n1 = ftanh(xn1 + r1 * gn1);
                float h1new = (n1 + z1 * (h1old - n1)) * l1gate;
                h1old = h1new;
                // ---- stage B: broadcast both h vectors in one latency stage ----
                #pragma unroll
                for (int kk = 0; kk < 16; kk++) h0r[kk] = __shfl(h0new, k0 + kk, 64);
                #pragma unroll
                for (int kk = 0; kk < 16; kk++) h1r[kk] = __shfl(h1new, k0 + kk, 64);
                // ---- xg1 partials for next iteration's L1 (on fresh h0) ----
                xq0 = hlf ? 0.f : bih1r[0];
                xq1 = hlf ? 0.f : bih1r[1];
                xq2 = hlf ? 0.f : bih1r[2];
                #pragma unroll
                for (int k = 0; k < 16; k++) {
                    xq0 += wi1[0][k] * h0r[k];
                    xq1 += wi1[1][k] * h0r[k];
                    xq2 += wi1[2][k] * h0r[k];
                }
                l1gate = 1.f;
            }
        }
    }

    // ---- pipeline epilogue: L1(LSEQ-1) ----
    {
        float g0 = hlf ? 0.f : bhh1r[0];
        float g1 = hlf ? 0.f : bhh1r[1];
        float g2 = hlf ? 0.f : bhh1r[2];
        #pragma unroll
        for (int k = 0; k < 16; k++) {
            g0 += wh1[0][k] * h1r[k];
            g1 += wh1[1][k] * h1r[k];
            g2 += wh1[2][k] * h1r[k];
        }
        float s1r = xq0 + g0;      s1r += __shfl_xor(s1r, 32, 64);
        float s1z = xq1 + g1;      s1z += __shfl_xor(s1z, 32, 64);
        float xn1 = xq2;           xn1 += __shfl_xor(xn1, 32, 64);
        float gn1 = g2;            gn1 += __shfl_xor(gn1, 32, 64);
        float r1 = fsig(s1r);
        float z1 = fsig(s1z);
        float n1 = ftanh(xn1 + r1 * gn1);
        float h1new = n1 + z1 * (h1old - n1);
        if (!hlf) h1L[j] = h1new;
    }

    // ---- head MLP + weighted accumulation ----
    if (tid < 32) {
        float s = bh1[e * NHU + tid];
        const float* wr = Wh1 + ((size_t)e * NHU + tid) * NH;
        #pragma unroll
        for (int d = 0; d < NH; d++) s += wr[d] * h1L[d];
        float hid = fmaxf(s, 0.f);
        float c = hid * Wh2[e * NHU + tid];
        #pragma unroll
        for (int off = 16; off > 0; off >>= 1) c += __shfl_down(c, off, 64);
        if (tid == 0) atomicAdd(out + b, wgt * (c + bh2[e]));
    }
}

extern "C" void kernel_launch(void* const* d_in, const int* in_sizes, int n_in,
                              void* d_out, int out_size, void* d_ws, size_t ws_size,
                              hipStream_t stream) {
    const float* x       = (const float*)d_in[0];
    const int*   horizon = (const int*)  d_in[1];
    const float* W_in    = (const float*)d_in[2];
    const float* b_in    = (const float*)d_in[3];
    const float* emb     = (const float*)d_in[4];
    const float* W_gate  = (const float*)d_in[5];
    const float* b_gate  = (const float*)d_in[6];
    const float* Wih0    = (const float*)d_in[7];
    const float* Whh0    = (const float*)d_in[8];
    const float* bih0    = (const float*)d_in[9];
    const float* bhh0    = (const float*)d_in[10];
    const float* Wih1    = (const float*)d_in[11];
    const float* Whh1    = (const float*)d_in[12];
    const float* bih1    = (const float*)d_in[13];
    const float* bhh1    = (const float*)d_in[14];
    const float* Wh1     = (const float*)d_in[15];
    const float* bh1     = (const float*)d_in[16];
    const float* Wh2     = (const float*)d_in[17];
    const float* bh2     = (const float*)d_in[18];
    float* out = (float*)d_out;
    float* Cg  = (float*)d_ws;   // NE*NF*G3 floats = 76.8 KB

    hipMemsetAsync(d_out, 0, NB * sizeof(float), stream);
    compute_C_kernel<<<dim3(NE), dim3(256), 0, stream>>>(Wih0, W_in, Cg);
    moe_gru_kernel<<<dim3(NB * NE), dim3(64), 0, stream>>>(
        x, horizon, emb, W_gate, b_gate, b_in,
        Wih0, Whh0, bih0, bhh0, Wih1, Whh1, bih1, bhh1,
        Wh1, bh1, Wh2, bh2, Cg, out);
}

// Round 4
// 1614.428 us; speedup vs baseline: 1.4536x; 1.4536x over previous
//
#include <hip/hip_runtime.h>
#include <math.h>

#define NB   256
#define LSEQ 1800
#define NF   50
#define NE   4
#define NH   32
#define G3   96
#define ND   64
#define NHU  32
#define CHUNK 60
#define TBLK  12
#define NCHUNK (LSEQ / CHUNK)   // 30
#define NBLK   (CHUNK / TBLK)   // 5

typedef float v2f __attribute__((ext_vector_type(2)));

__device__ __forceinline__ v2f v2fma(v2f a, v2f b, v2f c) {
    return __builtin_elementwise_fma(a, b, c);
}
__device__ __forceinline__ v2f mkv2(float a, float b) { v2f t; t.x = a; t.y = b; return t; }
__device__ __forceinline__ v2f splat2(float s) { v2f t; t.x = s; t.y = s; return t; }

// ---------------------------------------------------------------------------
// Kernel 1: fold input projection into layer-0 input weights.
// Cg[e][f][g] = sum_d Wih0[e][g][d] * W_in[d][f]
// ---------------------------------------------------------------------------
__global__ void compute_C_kernel(const float* __restrict__ Wih0,
                                 const float* __restrict__ W_in,
                                 float* __restrict__ Cg) {
    int e = blockIdx.x;
    for (int idx = threadIdx.x; idx < NF * G3; idx += blockDim.x) {
        int f = idx / G3;
        int g = idx - f * G3;
        const float* wr = Wih0 + ((size_t)e * G3 + g) * ND;
        float s = 0.f;
        #pragma unroll 8
        for (int d = 0; d < ND; d++) s += wr[d] * W_in[d * NF + f];
        Cg[(size_t)e * NF * G3 + idx] = s;
    }
}

// Fast transcendentals on v_exp_f32 / v_rcp_f32.
__device__ __forceinline__ float fsig(float x) {
    float e = __builtin_amdgcn_exp2f(-1.442695041f * x);
    return __builtin_amdgcn_rcpf(1.f + e);
}
__device__ __forceinline__ float ftanh(float x) {
    x = fmaxf(x, -20.f);
    float e = __builtin_amdgcn_exp2f(-2.885390082f * x);
    return (1.f - e) * __builtin_amdgcn_rcpf(1.f + e);
}

// ---------------------------------------------------------------------------
// One 64-thread (single-wave) block per (batch, expert); unrouted blocks exit.
// Full-dot role split with 1-step skew:
//   half 0 lane j: L0 row j, full 32-dots over h0  -> h0new_j directly (no reduce)
//   half 1 lane j: L1 row j (one step behind): xg1 = Wih1_j . h0 (full dots,
//                  no reduce) + gh1 = Whh1_j . h1 (k-half dots, 3 shfl_xor)
// Both halves execute the SAME instruction stream (weights differ per lane).
// h exchange: one ds_write_b32 (h0 from half0, h1 from half1 in the same
// instruction) + b128 broadcast reads. Single wave => no barriers.
// ---------------------------------------------------------------------------
__global__ __launch_bounds__(64, 1)
void moe_gru_kernel(const float* __restrict__ x,
                    const int*   __restrict__ horizon,
                    const float* __restrict__ emb,
                    const float* __restrict__ W_gate,
                    const float* __restrict__ b_gate,
                    const float* __restrict__ b_in,
                    const float* __restrict__ Wih0,
                    const float* __restrict__ Whh0,
                    const float* __restrict__ bih0,
                    const float* __restrict__ bhh0,
                    const float* __restrict__ Wih1,
                    const float* __restrict__ Whh1,
                    const float* __restrict__ bih1,
                    const float* __restrict__ bhh1,
                    const float* __restrict__ Wh1,
                    const float* __restrict__ bh1,
                    const float* __restrict__ Wh2,
                    const float* __restrict__ bh2,
                    const float* __restrict__ Cg,
                    float* __restrict__ out) {
    __shared__ __align__(16) float smem[3008 + 64 + 64 + 32 + 32];
    float* xs  = smem;                  // [f][CHUNK] transposed x chunk
    float* heL = smem + 3008;           // 64: h_embed
    float* bbL = heL + 64;              // 64: b_in + h_embed
    float* h0L = bbL + 64;              // 32
    float* h1L = h0L + 32;              // 32

    const int bid = blockIdx.x;
    const int b   = bid >> 2;
    const int e   = bid & 3;
    const int tid = threadIdx.x;
    const int j   = tid & 31;
    const int hlf = tid >> 5;
    const int k0h = hlf << 4;

    // ---- stage h_embed / (b_in + h_embed) (wave-synchronous) ----
    {
        int hor = horizon[b];
        float he = emb[(size_t)hor * ND + tid];
        heL[tid] = he;
        bbL[tid] = he + b_in[tid];
    }

    // ---- gating (every thread computes identically) ----
    float lg[NE];
    #pragma unroll
    for (int q = 0; q < NE; q++) {
        float s = b_gate[q];
        for (int d = 0; d < ND; d++) s += heL[d] * W_gate[q * ND + d];
        lg[q] = s;
    }
    int i1 = 0;
    #pragma unroll
    for (int q = 1; q < NE; q++) if (lg[q] > lg[i1]) i1 = q;
    int i2 = (i1 == 0) ? 1 : 0;
    #pragma unroll
    for (int q = 0; q < NE; q++) if (q != i1 && lg[q] > lg[i2]) i2 = q;
    if (e != i1 && e != i2) return;          // block-uniform
    const float ex2 = expf(lg[i2] - lg[i1]);
    const float wgt = (e == i1) ? (1.f / (1.f + ex2)) : (ex2 / (1.f + ex2));

    // ---- per-lane weights ----
    // selA: half0 -> Whh0 rows {j, j+32, j+64}; half1 -> Wih1 rows (full 32-k)
    v2f sA0[16], sA1[16], sA2[16];
    // wB: Whh1 rows {j, j+32, j+64}, k-half [k0h, k0h+16)
    v2f wB0[8], wB1[8], wB2[8];
    {
        const float* baseA = (hlf ? Wih1 : Whh0) + (size_t)e * G3 * NH;
        const float* rA0 = baseA + (size_t)j * NH;
        const float* rA1 = baseA + (size_t)(j + 32) * NH;
        const float* rA2 = baseA + (size_t)(j + 64) * NH;
        #pragma unroll
        for (int q4 = 0; q4 < 8; q4++) {
            float4 qa = ((const float4*)rA0)[q4];
            sA0[2*q4] = mkv2(qa.x, qa.y); sA0[2*q4+1] = mkv2(qa.z, qa.w);
            float4 qb = ((const float4*)rA1)[q4];
            sA1[2*q4] = mkv2(qb.x, qb.y); sA1[2*q4+1] = mkv2(qb.z, qb.w);
            float4 qc = ((const float4*)rA2)[q4];
            sA2[2*q4] = mkv2(qc.x, qc.y); sA2[2*q4+1] = mkv2(qc.z, qc.w);
        }
        const float* baseB = Whh1 + (size_t)e * G3 * NH;
        const float* rB0 = baseB + (size_t)j * NH + k0h;
        const float* rB1 = baseB + (size_t)(j + 32) * NH + k0h;
        const float* rB2 = baseB + (size_t)(j + 64) * NH + k0h;
        #pragma unroll
        for (int q4 = 0; q4 < 4; q4++) {
            float4 qa = ((const float4*)rB0)[q4];
            wB0[2*q4] = mkv2(qa.x, qa.y); wB0[2*q4+1] = mkv2(qa.z, qa.w);
            float4 qb = ((const float4*)rB1)[q4];
            wB1[2*q4] = mkv2(qb.x, qb.y); wB1[2*q4+1] = mkv2(qb.z, qb.w);
            float4 qc = ((const float4*)rB2)[q4];
            wB2[2*q4] = mkv2(qc.x, qc.y); wB2[2*q4+1] = mkv2(qc.z, qc.w);
        }
    }
    const float selb0 = hlf ? bih1[e*G3 + j]      : bhh0[e*G3 + j];
    const float selb1 = hlf ? bih1[e*G3 + j + 32] : bhh0[e*G3 + j + 32];
    const float selb2 = hlf ? bih1[e*G3 + j + 64] : bhh0[e*G3 + j + 64];
    const float whb0  = hlf ? 0.f : bhh1[e*G3 + j];
    const float whb1  = hlf ? 0.f : bhh1[e*G3 + j + 32];
    const float whb2  = hlf ? 0.f : bhh1[e*G3 + j + 64];

    // xg0 folded weights in registers: features fg = 25*hlf + [0,25)
    float wx0[25], wx1[25], wx2[25];
    {
        const float* cgb = Cg + (size_t)e * NF * G3;
        #pragma unroll
        for (int f = 0; f < 25; f++) {
            int fg = 25 * hlf + f;
            wx0[f] = cgb[fg * G3 + j];
            wx1[f] = cgb[fg * G3 + j + 32];
            wx2[f] = cgb[fg * G3 + j + 64];
        }
    }
    // dreg = bih0 + Wih0 @ (b_in + h_embed), added once (half0 side of reduce)
    float dreg0, dreg1, dreg2;
    {
        float s0 = bih0[e*G3 + j], s1 = bih0[e*G3 + j + 32], s2 = bih0[e*G3 + j + 64];
        const float* w0 = Wih0 + ((size_t)e * G3 + j) * ND;
        const float* w1 = Wih0 + ((size_t)e * G3 + j + 32) * ND;
        const float* w2 = Wih0 + ((size_t)e * G3 + j + 64) * ND;
        for (int d = 0; d < ND; d++) {
            float bb = bbL[d];
            s0 += w0[d] * bb; s1 += w1[d] * bb; s2 += w2[d] * bb;
        }
        dreg0 = hlf ? 0.f : s0;
        dreg1 = hlf ? 0.f : s1;
        dreg2 = hlf ? 0.f : s2;
    }

    // ---- pipeline state ----
    v2f h0v[16], h1v[8];
    #pragma unroll
    for (int k = 0; k < 16; k++) h0v[k] = splat2(0.f);
    #pragma unroll
    for (int k = 0; k < 8; k++)  h1v[k] = splat2(0.f);
    float hold = 0.f;                    // half0: h0_j ; half1: h1_j (skewed)
    float lmul = hlf ? 0.f : 1.f;        // neutralizes the fake first L1 step
    float* hptr = (hlf ? h1L : h0L) + j;

    const float* xg = x + (size_t)b * LSEQ * NF;

    for (int ch = 0; ch < NCHUNK; ch++) {
        // stage x chunk (contiguous float4 global loads), transpose to [f][t]
        {
            const float4* xc4 = (const float4*)(xg + (size_t)ch * CHUNK * NF);
            for (int i4 = tid; i4 < (CHUNK * NF) / 4; i4 += 64) {
                float4 v = xc4[i4];
                int idx = i4 * 4;
                #pragma unroll
                for (int u = 0; u < 4; u++) {
                    int id = idx + u;
                    int it = (int)(((unsigned)id * 5243u) >> 18);   // id/50
                    int f  = id - it * 50;
                    float val = (u == 0) ? v.x : (u == 1) ? v.y : (u == 2) ? v.z : v.w;
                    xs[f * CHUNK + it] = val;
                }
            }
        }

        for (int blk = 0; blk < NBLK; blk++) {
            const int ib0 = blk * TBLK;
            // ---- xg0 partials for TBLK steps (f-split across halves) ----
            v2f a0[6], a1[6], a2[6];
            #pragma unroll
            for (int p = 0; p < 6; p++) {
                a0[p] = splat2(dreg0); a1[p] = splat2(dreg1); a2[p] = splat2(dreg2);
            }
            #pragma unroll 5
            for (int f = 0; f < 25; f++) {
                const float4* xp = (const float4*)(xs + (25 * hlf + f) * CHUNK + ib0);
                float4 xa = xp[0], xb = xp[1], xc4 = xp[2];
                v2f xv[6] = { mkv2(xa.x, xa.y), mkv2(xa.z, xa.w),
                              mkv2(xb.x, xb.y), mkv2(xb.z, xb.w),
                              mkv2(xc4.x, xc4.y), mkv2(xc4.z, xc4.w) };
                v2f w0 = splat2(wx0[f]), w1 = splat2(wx1[f]), w2 = splat2(wx2[f]);
                #pragma unroll
                for (int p = 0; p < 6; p++) {
                    a0[p] = v2fma(w0, xv[p], a0[p]);
                    a1[p] = v2fma(w1, xv[p], a1[p]);
                    a2[p] = v2fma(w2, xv[p], a2[p]);
                }
            }
            // cross-half reduce of xg0 (off the per-step chain)
            #pragma unroll
            for (int p = 0; p < 6; p++) {
                a0[p].x += __shfl_xor(a0[p].x, 32, 64); a0[p].y += __shfl_xor(a0[p].y, 32, 64);
                a1[p].x += __shfl_xor(a1[p].x, 32, 64); a1[p].y += __shfl_xor(a1[p].y, 32, 64);
                a2[p].x += __shfl_xor(a2[p].x, 32, 64); a2[p].y += __shfl_xor(a2[p].y, 32, 64);
            }

            // ---- TBLK pipelined steps: L0(t) on half0 || L1(t-1) on half1 ----
            #pragma unroll
            for (int i = 0; i < TBLK; i++) {
                const float ac0 = a0[i >> 1][i & 1];
                const float ac1 = a1[i >> 1][i & 1];
                const float ac2 = a2[i >> 1][i & 1];
                // full dots over h0 (half0: Whh0; half1: Wih1)
                v2f dA0 = mkv2(selb0, 0.f), dA1 = mkv2(selb1, 0.f), dA2 = mkv2(selb2, 0.f);
                #pragma unroll
                for (int k = 0; k < 16; k++) {
                    dA0 = v2fma(sA0[k], h0v[k], dA0);
                    dA1 = v2fma(sA1[k], h0v[k], dA1);
                    dA2 = v2fma(sA2[k], h0v[k], dA2);
                }
                // k-half dots over h1 (Whh1), reduced across halves
                v2f dB0 = mkv2(whb0, 0.f), dB1 = mkv2(whb1, 0.f), dB2 = mkv2(whb2, 0.f);
                #pragma unroll
                for (int k = 0; k < 8; k++) {
                    dB0 = v2fma(wB0[k], h1v[k], dB0);
                    dB1 = v2fma(wB1[k], h1v[k], dB1);
                    dB2 = v2fma(wB2[k], h1v[k], dB2);
                }
                float A0 = dA0.x + dA0.y, A1 = dA1.x + dA1.y, A2 = dA2.x + dA2.y;
                float B0 = dB0.x + dB0.y, B1 = dB1.x + dB1.y, B2 = dB2.x + dB2.y;
                float R0 = B0 + __shfl_xor(B0, 32, 64);
                float R1 = B1 + __shfl_xor(B1, 32, 64);
                float R2 = B2 + __shfl_xor(B2, 32, 64);
                // gate assembly (uniform instructions, per-half operand select)
                float o0   = hlf ? R0 : ac0;
                float o1   = hlf ? R1 : ac1;
                float npre = hlf ? A2 : ac2;
                float gn   = hlf ? R2 : A2;
                float r = fsig(A0 + o0);
                float z = fsig(A1 + o1);
                float n = ftanh(npre + r * gn);
                float hnew = (n + z * (hold - n)) * lmul;
                hold = hnew;
                lmul = 1.f;
                hptr[0] = hnew;                       // one ds_write for both h0/h1
                // broadcast read-back
                const float4* h0q = (const float4*)h0L;
                #pragma unroll
                for (int q4 = 0; q4 < 8; q4++) {
                    float4 qq = h0q[q4];
                    h0v[2*q4]   = mkv2(qq.x, qq.y);
                    h0v[2*q4+1] = mkv2(qq.z, qq.w);
                }
                const float4* h1q = (const float4*)(h1L + k0h);
                #pragma unroll
                for (int q4 = 0; q4 < 4; q4++) {
                    float4 qq = h1q[q4];
                    h1v[2*q4]   = mkv2(qq.x, qq.y);
                    h1v[2*q4+1] = mkv2(qq.z, qq.w);
                }
            }
        }
    }

    // ---- epilogue: L1(LSEQ-1) (results used from half1 only) ----
    {
        v2f dA0 = mkv2(selb0, 0.f), dA1 = mkv2(selb1, 0.f), dA2 = mkv2(selb2, 0.f);
        #pragma unroll
        for (int k = 0; k < 16; k++) {
            dA0 = v2fma(sA0[k], h0v[k], dA0);
            dA1 = v2fma(sA1[k], h0v[k], dA1);
            dA2 = v2fma(sA2[k], h0v[k], dA2);
        }
        v2f dB0 = mkv2(whb0, 0.f), dB1 = mkv2(whb1, 0.f), dB2 = mkv2(whb2, 0.f);
        #pragma unroll
        for (int k = 0; k < 8; k++) {
            dB0 = v2fma(wB0[k], h1v[k], dB0);
            dB1 = v2fma(wB1[k], h1v[k], dB1);
            dB2 = v2fma(wB2[k], h1v[k], dB2);
        }
        float A0 = dA0.x + dA0.y, A1 = dA1.x + dA1.y, A2 = dA2.x + dA2.y;
        float B0 = dB0.x + dB0.y, B1 = dB1.x + dB1.y, B2 = dB2.x + dB2.y;
        float R0 = B0 + __shfl_xor(B0, 32, 64);
        float R1 = B1 + __shfl_xor(B1, 32, 64);
        float R2 = B2 + __shfl_xor(B2, 32, 64);
        float r = fsig(A0 + R0);
        float z = fsig(A1 + R1);
        float n = ftanh(A2 + r * R2);
        float hfin = n + z * (hold - n);
        if (hlf) h1L[j] = hfin;
    }

    // ---- head MLP + weighted accumulation ----
    if (tid < 32) {
        float s = bh1[e * NHU + tid];
        const float* wr = Wh1 + ((size_t)e * NHU + tid) * NH;
        #pragma unroll
        for (int d = 0; d < NH; d++) s += wr[d] * h1L[d];
        float hid = fmaxf(s, 0.f);
        float c = hid * Wh2[e * NHU + tid];
        #pragma unroll
        for (int off = 16; off > 0; off >>= 1) c += __shfl_down(c, off, 64);
        if (tid == 0) atomicAdd(out + b, wgt * (c + bh2[e]));
    }
}

extern "C" void kernel_launch(void* const* d_in, const int* in_sizes, int n_in,
                              void* d_out, int out_size, void* d_ws, size_t ws_size,
                              hipStream_t stream) {
    const float* x       = (const float*)d_in[0];
    const int*   horizon = (const int*)  d_in[1];
    const float* W_in    = (const float*)d_in[2];
    const float* b_in    = (const float*)d_in[3];
    const float* emb     = (const float*)d_in[4];
    const float* W_gate  = (const float*)d_in[5];
    const float* b_gate  = (const float*)d_in[6];
    const float* Wih0    = (const float*)d_in[7];
    const float* Whh0    = (const float*)d_in[8];
    const float* bih0    = (const float*)d_in[9];
    const float* bhh0    = (const float*)d_in[10];
    const float* Wih1    = (const float*)d_in[11];
    const float* Whh1    = (const float*)d_in[12];
    const float* bih1    = (const float*)d_in[13];
    const float* bhh1    = (const float*)d_in[14];
    const float* Wh1     = (const float*)d_in[15];
    const float* bh1     = (const float*)d_in[16];
    const float* Wh2     = (const float*)d_in[17];
    const float* bh2     = (const float*)d_in[18];
    float* out = (float*)d_out;
    float* Cg  = (float*)d_ws;   // NE*NF*G3 floats = 76.8 KB

    hipMemsetAsync(d_out, 0, NB * sizeof(float), stream);
    compute_C_kernel<<<dim3(NE), dim3(256), 0, stream>>>(Wih0, W_in, Cg);
    moe_gru_kernel<<<dim3(NB * NE), dim3(64), 0, stream>>>(
        x, horizon, emb, W_gate, b_gate, b_in,
        Wih0, Whh0, bih0, bhh0, Wih1, Whh1, bih1, bhh1,
        Wh1, bh1, Wh2, bh2, Cg, out);
}

// Round 5
// 1415.157 us; speedup vs baseline: 1.6583x; 1.1408x over previous
//
#include <hip/hip_runtime.h>
#include <math.h>

#define NB   256
#define LSEQ 1800
#define NF   50
#define NE   4
#define NH   32
#define G3   96
#define ND   64
#define NHU  32
#define CHUNK 60
#define TBLK  6
#define NCHUNK (LSEQ / CHUNK)   // 30
#define NBLK   (CHUNK / TBLK)   // 10

typedef float v2f __attribute__((ext_vector_type(2)));

__device__ __forceinline__ v2f v2fma(v2f a, v2f b, v2f c) {
    return __builtin_elementwise_fma(a, b, c);
}
__device__ __forceinline__ v2f mkv2(float a, float b) { v2f t; t.x = a; t.y = b; return t; }
__device__ __forceinline__ v2f splat2(float s) { v2f t; t.x = s; t.y = s; return t; }

// ---------------------------------------------------------------------------
// Kernel 1: fold input projection into layer-0 input weights.
// Cg[e][f][g] = sum_d Wih0[e][g][d] * W_in[d][f]
// ---------------------------------------------------------------------------
__global__ void compute_C_kernel(const float* __restrict__ Wih0,
                                 const float* __restrict__ W_in,
                                 float* __restrict__ Cg) {
    int e = blockIdx.x;
    for (int idx = threadIdx.x; idx < NF * G3; idx += blockDim.x) {
        int f = idx / G3;
        int g = idx - f * G3;
        const float* wr = Wih0 + ((size_t)e * G3 + g) * ND;
        float s = 0.f;
        #pragma unroll 8
        for (int d = 0; d < ND; d++) s += wr[d] * W_in[d * NF + f];
        Cg[(size_t)e * NF * G3 + idx] = s;
    }
}

// Fast transcendentals on v_exp_f32 / v_rcp_f32.
__device__ __forceinline__ float fsig(float x) {
    float e = __builtin_amdgcn_exp2f(-1.442695041f * x);
    return __builtin_amdgcn_rcpf(1.f + e);
}
__device__ __forceinline__ float ftanh(float x) {
    x = fmaxf(x, -20.f);
    float e = __builtin_amdgcn_exp2f(-2.885390082f * x);
    return (1.f - e) * __builtin_amdgcn_rcpf(1.f + e);
}

// ---------------------------------------------------------------------------
// One 64-thread (single-wave) block per (batch, expert); unrouted blocks exit.
// Full-dot role split with 1-step skew:
//   half 0 lane j: L0(t) row j: full 32-dots over h0 (no reduce) + k-half of
//                  gh1 row j; half 1 lane j: L1(t-1): xg1 full dots over h0 +
//                  other k-half of gh1. One shfl_xor reduce stage (gh1 only).
// Register budget kept <= ~240 (hard cap 256): xg0 weights live in LDS (CT),
// TBLK=6 accumulators. No barriers: single wave.
// ---------------------------------------------------------------------------
__global__ __launch_bounds__(64, 1)
void moe_gru_kernel(const float* __restrict__ x,
                    const int*   __restrict__ horizon,
                    const float* __restrict__ emb,
                    const float* __restrict__ W_gate,
                    const float* __restrict__ b_gate,
                    const float* __restrict__ b_in,
                    const float* __restrict__ Wih0,
                    const float* __restrict__ Whh0,
                    const float* __restrict__ bih0,
                    const float* __restrict__ bhh0,
                    const float* __restrict__ Wih1,
                    const float* __restrict__ Whh1,
                    const float* __restrict__ bih1,
                    const float* __restrict__ bhh1,
                    const float* __restrict__ Wh1,
                    const float* __restrict__ bh1,
                    const float* __restrict__ Wh2,
                    const float* __restrict__ bh2,
                    const float* __restrict__ Cg,
                    float* __restrict__ out) {
    __shared__ __align__(16) float smem[4800 + 3008 + 64 + 64 + 32 + 32];
    float* CT  = smem;                  // [f][96] folded xg0 weights
    float* xs  = smem + 4800;           // [f][CHUNK] transposed x chunk
    float* heL = smem + 4800 + 3008;    // 64: h_embed
    float* bbL = heL + 64;              // 64: b_in + h_embed
    float* h0L = bbL + 64;              // 32
    float* h1L = h0L + 32;              // 32

    const int bid = blockIdx.x;
    const int b   = bid >> 2;
    const int e   = bid & 3;
    const int tid = threadIdx.x;
    const int j   = tid & 31;
    const int hlf = tid >> 5;
    const int k0h = hlf << 4;

    // ---- stage h_embed / (b_in + h_embed) (wave-synchronous) ----
    {
        int hor = horizon[b];
        float he = emb[(size_t)hor * ND + tid];
        heL[tid] = he;
        bbL[tid] = he + b_in[tid];
    }

    // ---- gating (every thread computes identically) ----
    float lg[NE];
    #pragma unroll
    for (int q = 0; q < NE; q++) {
        float s = b_gate[q];
        for (int d = 0; d < ND; d++) s += heL[d] * W_gate[q * ND + d];
        lg[q] = s;
    }
    int i1 = 0;
    #pragma unroll
    for (int q = 1; q < NE; q++) if (lg[q] > lg[i1]) i1 = q;
    int i2 = (i1 == 0) ? 1 : 0;
    #pragma unroll
    for (int q = 0; q < NE; q++) if (q != i1 && lg[q] > lg[i2]) i2 = q;
    if (e != i1 && e != i2) return;          // block-uniform
    const float ex2 = expf(lg[i2] - lg[i1]);
    const float wgt = (e == i1) ? (1.f / (1.f + ex2)) : (ex2 / (1.f + ex2));

    // ---- stage folded xg0 weights into LDS ----
    for (int idx = tid; idx < NF * G3; idx += 64)
        CT[idx] = Cg[(size_t)e * NF * G3 + idx];

    // ---- per-lane weights ----
    // selA: half0 -> Whh0 rows {j, j+32, j+64}; half1 -> Wih1 rows (full 32-k)
    v2f sA0[16], sA1[16], sA2[16];
    // wB: Whh1 rows {j, j+32, j+64}, k-half [k0h, k0h+16)
    v2f wB0[8], wB1[8], wB2[8];
    {
        const float* baseA = (hlf ? Wih1 : Whh0) + (size_t)e * G3 * NH;
        const float* rA0 = baseA + (size_t)j * NH;
        const float* rA1 = baseA + (size_t)(j + 32) * NH;
        const float* rA2 = baseA + (size_t)(j + 64) * NH;
        #pragma unroll
        for (int q4 = 0; q4 < 8; q4++) {
            float4 qa = ((const float4*)rA0)[q4];
            sA0[2*q4] = mkv2(qa.x, qa.y); sA0[2*q4+1] = mkv2(qa.z, qa.w);
            float4 qb = ((const float4*)rA1)[q4];
            sA1[2*q4] = mkv2(qb.x, qb.y); sA1[2*q4+1] = mkv2(qb.z, qb.w);
            float4 qc = ((const float4*)rA2)[q4];
            sA2[2*q4] = mkv2(qc.x, qc.y); sA2[2*q4+1] = mkv2(qc.z, qc.w);
        }
        const float* baseB = Whh1 + (size_t)e * G3 * NH;
        const float* rB0 = baseB + (size_t)j * NH + k0h;
        const float* rB1 = baseB + (size_t)(j + 32) * NH + k0h;
        const float* rB2 = baseB + (size_t)(j + 64) * NH + k0h;
        #pragma unroll
        for (int q4 = 0; q4 < 4; q4++) {
            float4 qa = ((const float4*)rB0)[q4];
            wB0[2*q4] = mkv2(qa.x, qa.y); wB0[2*q4+1] = mkv2(qa.z, qa.w);
            float4 qb = ((const float4*)rB1)[q4];
            wB1[2*q4] = mkv2(qb.x, qb.y); wB1[2*q4+1] = mkv2(qb.z, qb.w);
            float4 qc = ((const float4*)rB2)[q4];
            wB2[2*q4] = mkv2(qc.x, qc.y); wB2[2*q4+1] = mkv2(qc.z, qc.w);
        }
    }
    const float selb0 = hlf ? bih1[e*G3 + j]      : bhh0[e*G3 + j];
    const float selb1 = hlf ? bih1[e*G3 + j + 32] : bhh0[e*G3 + j + 32];
    const float selb2 = hlf ? bih1[e*G3 + j + 64] : bhh0[e*G3 + j + 64];
    const float whb0  = hlf ? 0.f : bhh1[e*G3 + j];
    const float whb1  = hlf ? 0.f : bhh1[e*G3 + j + 32];
    const float whb2  = hlf ? 0.f : bhh1[e*G3 + j + 64];

    // dreg = bih0 + Wih0 @ (b_in + h_embed), added once (half0 side of reduce)
    float dreg0, dreg1, dreg2;
    {
        float s0 = bih0[e*G3 + j], s1 = bih0[e*G3 + j + 32], s2 = bih0[e*G3 + j + 64];
        const float* w0 = Wih0 + ((size_t)e * G3 + j) * ND;
        const float* w1 = Wih0 + ((size_t)e * G3 + j + 32) * ND;
        const float* w2 = Wih0 + ((size_t)e * G3 + j + 64) * ND;
        for (int d = 0; d < ND; d++) {
            float bb = bbL[d];
            s0 += w0[d] * bb; s1 += w1[d] * bb; s2 += w2[d] * bb;
        }
        dreg0 = hlf ? 0.f : s0;
        dreg1 = hlf ? 0.f : s1;
        dreg2 = hlf ? 0.f : s2;
    }

    // ---- pipeline state ----
    v2f h0v[16], h1v[8];
    #pragma unroll
    for (int k = 0; k < 16; k++) h0v[k] = splat2(0.f);
    #pragma unroll
    for (int k = 0; k < 8; k++)  h1v[k] = splat2(0.f);
    float hold = 0.f;                    // half0: h0_j ; half1: h1_j (skewed)
    float lmul = hlf ? 0.f : 1.f;        // neutralizes the fake first L1 step
    float* hptr = (hlf ? h1L : h0L) + j;

    const float* xg = x + (size_t)b * LSEQ * NF;

    for (int ch = 0; ch < NCHUNK; ch++) {
        // stage x chunk (contiguous float4 global loads), transpose to [f][t]
        {
            const float4* xc4 = (const float4*)(xg + (size_t)ch * CHUNK * NF);
            for (int i4 = tid; i4 < (CHUNK * NF) / 4; i4 += 64) {
                float4 v = xc4[i4];
                int idx = i4 * 4;
                #pragma unroll
                for (int u = 0; u < 4; u++) {
                    int id = idx + u;
                    int it = (int)(((unsigned)id * 5243u) >> 18);   // id/50
                    int f  = id - it * 50;
                    float val = (u == 0) ? v.x : (u == 1) ? v.y : (u == 2) ? v.z : v.w;
                    xs[f * CHUNK + it] = val;
                }
            }
        }

        for (int blk = 0; blk < NBLK; blk++) {
            const int ib0 = blk * TBLK;
            // ---- xg0 partials for TBLK steps (f-split across halves) ----
            v2f a0[3], a1[3], a2[3];
            #pragma unroll
            for (int p = 0; p < 3; p++) {
                a0[p] = splat2(dreg0); a1[p] = splat2(dreg1); a2[p] = splat2(dreg2);
            }
            #pragma unroll 5
            for (int f = 0; f < 25; f++) {
                const int fg = 25 * hlf + f;
                float c0 = CT[fg * G3 + j];
                float c1 = CT[fg * G3 + j + 32];
                float c2 = CT[fg * G3 + j + 64];
                const float2* xp = (const float2*)(xs + fg * CHUNK + ib0);
                float2 xa = xp[0], xb = xp[1], xc2 = xp[2];
                v2f xv[3] = { mkv2(xa.x, xa.y), mkv2(xb.x, xb.y), mkv2(xc2.x, xc2.y) };
                v2f w0 = splat2(c0), w1 = splat2(c1), w2 = splat2(c2);
                #pragma unroll
                for (int p = 0; p < 3; p++) {
                    a0[p] = v2fma(w0, xv[p], a0[p]);
                    a1[p] = v2fma(w1, xv[p], a1[p]);
                    a2[p] = v2fma(w2, xv[p], a2[p]);
                }
            }
            // cross-half reduce of xg0 (off the per-step chain)
            #pragma unroll
            for (int p = 0; p < 3; p++) {
                a0[p].x += __shfl_xor(a0[p].x, 32, 64); a0[p].y += __shfl_xor(a0[p].y, 32, 64);
                a1[p].x += __shfl_xor(a1[p].x, 32, 64); a1[p].y += __shfl_xor(a1[p].y, 32, 64);
                a2[p].x += __shfl_xor(a2[p].x, 32, 64); a2[p].y += __shfl_xor(a2[p].y, 32, 64);
            }

            // ---- TBLK pipelined steps: L0(t) on half0 || L1(t-1) on half1 ----
            #pragma unroll
            for (int i = 0; i < TBLK; i++) {
                const float ac0 = a0[i >> 1][i & 1];
                const float ac1 = a1[i >> 1][i & 1];
                const float ac2 = a2[i >> 1][i & 1];
                // full dots over h0 (half0: Whh0; half1: Wih1)
                v2f dA0 = mkv2(selb0, 0.f), dA1 = mkv2(selb1, 0.f), dA2 = mkv2(selb2, 0.f);
                #pragma unroll
                for (int k = 0; k < 16; k++) {
                    dA0 = v2fma(sA0[k], h0v[k], dA0);
                    dA1 = v2fma(sA1[k], h0v[k], dA1);
                    dA2 = v2fma(sA2[k], h0v[k], dA2);
                }
                // k-half dots over h1 (Whh1), reduced across halves
                v2f dB0 = mkv2(whb0, 0.f), dB1 = mkv2(whb1, 0.f), dB2 = mkv2(whb2, 0.f);
                #pragma unroll
                for (int k = 0; k < 8; k++) {
                    dB0 = v2fma(wB0[k], h1v[k], dB0);
                    dB1 = v2fma(wB1[k], h1v[k], dB1);
                    dB2 = v2fma(wB2[k], h1v[k], dB2);
                }
                float A0 = dA0.x + dA0.y, A1 = dA1.x + dA1.y, A2 = dA2.x + dA2.y;
                float B0 = dB0.x + dB0.y, B1 = dB1.x + dB1.y, B2 = dB2.x + dB2.y;
                float R0 = B0 + __shfl_xor(B0, 32, 64);
                float R1 = B1 + __shfl_xor(B1, 32, 64);
                float R2 = B2 + __shfl_xor(B2, 32, 64);
                // gate assembly (uniform instructions, per-half operand select)
                float o0   = hlf ? R0 : ac0;
                float o1   = hlf ? R1 : ac1;
                float npre = hlf ? A2 : ac2;
                float gn   = hlf ? R2 : A2;
                float r = fsig(A0 + o0);
                float z = fsig(A1 + o1);
                float n = ftanh(npre + r * gn);
                float hnew = (n + z * (hold - n)) * lmul;
                hold = hnew;
                lmul = 1.f;
                hptr[0] = hnew;                       // one ds_write covers h0 & h1
                // broadcast read-back
                const float4* h0q = (const float4*)h0L;
                #pragma unroll
                for (int q4 = 0; q4 < 8; q4++) {
                    float4 qq = h0q[q4];
                    h0v[2*q4]   = mkv2(qq.x, qq.y);
                    h0v[2*q4+1] = mkv2(qq.z, qq.w);
                }
                const float4* h1q = (const float4*)(h1L + k0h);
                #pragma unroll
                for (int q4 = 0; q4 < 4; q4++) {
                    float4 qq = h1q[q4];
                    h1v[2*q4]   = mkv2(qq.x, qq.y);
                    h1v[2*q4+1] = mkv2(qq.z, qq.w);
                }
            }
        }
    }

    // ---- epilogue: L1(LSEQ-1) (results used from half1 only) ----
    {
        v2f dA0 = mkv2(selb0, 0.f), dA1 = mkv2(selb1, 0.f), dA2 = mkv2(selb2, 0.f);
        #pragma unroll
        for (int k = 0; k < 16; k++) {
            dA0 = v2fma(sA0[k], h0v[k], dA0);
            dA1 = v2fma(sA1[k], h0v[k], dA1);
            dA2 = v2fma(sA2[k], h0v[k], dA2);
        }
        v2f dB0 = mkv2(whb0, 0.f), dB1 = mkv2(whb1, 0.f), dB2 = mkv2(whb2, 0.f);
        #pragma unroll
        for (int k = 0; k < 8; k++) {
            dB0 = v2fma(wB0[k], h1v[k], dB0);
            dB1 = v2fma(wB1[k], h1v[k], dB1);
            dB2 = v2fma(wB2[k], h1v[k], dB2);
        }
        float A0 = dA0.x + dA0.y, A1 = dA1.x + dA1.y, A2 = dA2.x + dA2.y;
        float B0 = dB0.x + dB0.y, B1 = dB1.x + dB1.y, B2 = dB2.x + dB2.y;
        float R0 = B0 + __shfl_xor(B0, 32, 64);
        float R1 = B1 + __shfl_xor(B1, 32, 64);
        float R2 = B2 + __shfl_xor(B2, 32, 64);
        float r = fsig(A0 + R0);
        float z = fsig(A1 + R1);
        float n = ftanh(A2 + r * R2);
        float hfin = n + z * (hold - n);
        if (hlf) h1L[j] = hfin;
    }

    // ---- head MLP + weighted accumulation ----
    if (tid < 32) {
        float s = bh1[e * NHU + tid];
        const float* wr = Wh1 + ((size_t)e * NHU + tid) * NH;
        #pragma unroll
        for (int d = 0; d < NH; d++) s += wr[d] * h1L[d];
        float hid = fmaxf(s, 0.f);
        float c = hid * Wh2[e * NHU + tid];
        #pragma unroll
        for (int off = 16; off > 0; off >>= 1) c += __shfl_down(c, off, 64);
        if (tid == 0) atomicAdd(out + b, wgt * (c + bh2[e]));
    }
}

extern "C" void kernel_launch(void* const* d_in, const int* in_sizes, int n_in,
                              void* d_out, int out_size, void* d_ws, size_t ws_size,
                              hipStream_t stream) {
    const float* x       = (const float*)d_in[0];
    const int*   horizon = (const int*)  d_in[1];
    const float* W_in    = (const float*)d_in[2];
    const float* b_in    = (const float*)d_in[3];
    const float* emb     = (const float*)d_in[4];
    const float* W_gate  = (const float*)d_in[5];
    const float* b_gate  = (const float*)d_in[6];
    const float* Wih0    = (const float*)d_in[7];
    const float* Whh0    = (const float*)d_in[8];
    const float* bih0    = (const float*)d_in[9];
    const float* bhh0    = (const float*)d_in[10];
    const float* Wih1    = (const float*)d_in[11];
    const float* Whh1    = (const float*)d_in[12];
    const float* bih1    = (const float*)d_in[13];
    const float* bhh1    = (const float*)d_in[14];
    const float* Wh1     = (const float*)d_in[15];
    const float* bh1     = (const float*)d_in[16];
    const float* Wh2     = (const float*)d_in[17];
    const float* bh2     = (const float*)d_in[18];
    float* out = (float*)d_out;
    float* Cg  = (float*)d_ws;   // NE*NF*G3 floats = 76.8 KB

    hipMemsetAsync(d_out, 0, NB * sizeof(float), stream);
    compute_C_kernel<<<dim3(NE), dim3(256), 0, stream>>>(Wih0, W_in, Cg);
    moe_gru_kernel<<<dim3(NB * NE), dim3(64), 0, stream>>>(
        x, horizon, emb, W_gate, b_gate, b_in,
        Wih0, Whh0, bih0, bhh0, Wih1, Whh1, bih1, bhh1,
        Wh1, bh1, Wh2, bh2, Cg, out);
}

// Round 6
// 1409.425 us; speedup vs baseline: 1.6650x; 1.0041x over previous
//
#include <hip/hip_runtime.h>
#include <math.h>

#define NB   256
#define LSEQ 1800
#define NF   50
#define NE   4
#define NH   32
#define G3   96
#define ND   64
#define NHU  32
#define CHUNK 72
#define TBLK  8
#define NCHUNK (LSEQ / CHUNK)   // 25
#define NBLK   (CHUNK / TBLK)   // 9

typedef float v2f __attribute__((ext_vector_type(2)));

__device__ __forceinline__ v2f v2fma(v2f a, v2f b, v2f c) {
    return __builtin_elementwise_fma(a, b, c);
}
__device__ __forceinline__ v2f mkv2(float a, float b) { v2f t; t.x = a; t.y = b; return t; }
__device__ __forceinline__ v2f splat2(float s) { v2f t; t.x = s; t.y = s; return t; }

// ---------------------------------------------------------------------------
// Kernel 1: fold input projection into layer-0 input weights.
// Layout: Cg[e][f][j][c] = sum_d Wih0[e][j+32c][d] * W_in[d][f]  (c in 0..2,
// 4th lane padding) -> one b128 read per (lane, feature) in the main kernel.
// ---------------------------------------------------------------------------
__global__ void compute_C_kernel(const float* __restrict__ Wih0,
                                 const float* __restrict__ W_in,
                                 float* __restrict__ Cg) {
    int e = blockIdx.x;
    for (int idx = threadIdx.x; idx < NF * G3; idx += blockDim.x) {
        int f = idx / G3;
        int g = idx - f * G3;
        const float* wr = Wih0 + ((size_t)e * G3 + g) * ND;
        float s = 0.f;
        #pragma unroll 8
        for (int d = 0; d < ND; d++) s += wr[d] * W_in[d * NF + f];
        int jj = g & 31, c = g >> 5;
        Cg[(((size_t)e * NF + f) * 32 + jj) * 4 + c] = s;
    }
}

// Fast transcendentals on v_exp_f32 / v_rcp_f32.
__device__ __forceinline__ float fsig(float x) {
    float e = __builtin_amdgcn_exp2f(-1.442695041f * x);
    return __builtin_amdgcn_rcpf(1.f + e);
}
__device__ __forceinline__ float ftanh(float x) {
    x = fmaxf(x, -20.f);
    float e = __builtin_amdgcn_exp2f(-2.885390082f * x);
    return (1.f - e) * __builtin_amdgcn_rcpf(1.f + e);
}

// ---------------------------------------------------------------------------
// One 64-thread (single-wave) block per (batch, expert); unrouted blocks exit.
// Role split with 1-step skew: half0 lane j = L0(t) row j (full 32-dots over
// h0, no reduce); half1 lane j = L1(t-1) row j (xg1 full dots over h0 + gh1
// k-half dots over h1, one shfl_xor reduce). Step body ordered so the gh1
// swizzle latency is covered by the A-dots. No barriers (single wave).
// ---------------------------------------------------------------------------
__global__ __launch_bounds__(64, 1)
void moe_gru_kernel(const float* __restrict__ x,
                    const int*   __restrict__ horizon,
                    const float* __restrict__ emb,
                    const float* __restrict__ W_gate,
                    const float* __restrict__ b_gate,
                    const float* __restrict__ b_in,
                    const float* __restrict__ Wih0,
                    const float* __restrict__ Whh0,
                    const float* __restrict__ bih0,
                    const float* __restrict__ bhh0,
                    const float* __restrict__ Wih1,
                    const float* __restrict__ Whh1,
                    const float* __restrict__ bih1,
                    const float* __restrict__ bhh1,
                    const float* __restrict__ Wh1,
                    const float* __restrict__ bh1,
                    const float* __restrict__ Wh2,
                    const float* __restrict__ bh2,
                    const float* __restrict__ Cg,
                    float* __restrict__ out) {
    __shared__ __align__(16) float smem[6400 + 3600 + 64 + 64 + 32 + 32];
    float* CT  = smem;                  // [f][32][4] folded xg0 weights (b128/lane)
    float* xs  = smem + 6400;           // [f][CHUNK] transposed x chunk
    float* heL = smem + 6400 + 3600;    // 64: h_embed
    float* bbL = heL + 64;              // 64: b_in + h_embed
    float* h0L = bbL + 64;              // 32
    float* h1L = h0L + 32;              // 32

    const int bid = blockIdx.x;
    const int b   = bid >> 2;
    const int e   = bid & 3;
    const int tid = threadIdx.x;
    const int j   = tid & 31;
    const int hlf = tid >> 5;
    const int k0h = hlf << 4;

    // ---- stage h_embed / (b_in + h_embed) (wave-synchronous) ----
    {
        int hor = horizon[b];
        float he = emb[(size_t)hor * ND + tid];
        heL[tid] = he;
        bbL[tid] = he + b_in[tid];
    }

    // ---- gating (every thread computes identically) ----
    float lg[NE];
    #pragma unroll
    for (int q = 0; q < NE; q++) {
        float s = b_gate[q];
        for (int d = 0; d < ND; d++) s += heL[d] * W_gate[q * ND + d];
        lg[q] = s;
    }
    int i1 = 0;
    #pragma unroll
    for (int q = 1; q < NE; q++) if (lg[q] > lg[i1]) i1 = q;
    int i2 = (i1 == 0) ? 1 : 0;
    #pragma unroll
    for (int q = 0; q < NE; q++) if (q != i1 && lg[q] > lg[i2]) i2 = q;
    if (e != i1 && e != i2) return;          // block-uniform
    const float ex2 = expf(lg[i2] - lg[i1]);
    const float wgt = (e == i1) ? (1.f / (1.f + ex2)) : (ex2 / (1.f + ex2));

    // ---- stage folded xg0 weights into LDS (float4 copy, 25 iters/lane) ----
    {
        const float4* src = (const float4*)(Cg + (size_t)e * NF * 128);
        float4* dst = (float4*)CT;
        for (int idx = tid; idx < NF * 32; idx += 64) dst[idx] = src[idx];
    }

    // ---- per-lane weights ----
    // selA: half0 -> Whh0 rows {j, j+32, j+64}; half1 -> Wih1 rows (full 32-k)
    v2f sA0[16], sA1[16], sA2[16];
    // wB: Whh1 rows {j, j+32, j+64}, k-half [k0h, k0h+16)
    v2f wB0[8], wB1[8], wB2[8];
    {
        const float* baseA = (hlf ? Wih1 : Whh0) + (size_t)e * G3 * NH;
        const float* rA0 = baseA + (size_t)j * NH;
        const float* rA1 = baseA + (size_t)(j + 32) * NH;
        const float* rA2 = baseA + (size_t)(j + 64) * NH;
        #pragma unroll
        for (int q4 = 0; q4 < 8; q4++) {
            float4 qa = ((const float4*)rA0)[q4];
            sA0[2*q4] = mkv2(qa.x, qa.y); sA0[2*q4+1] = mkv2(qa.z, qa.w);
            float4 qb = ((const float4*)rA1)[q4];
            sA1[2*q4] = mkv2(qb.x, qb.y); sA1[2*q4+1] = mkv2(qb.z, qb.w);
            float4 qc = ((const float4*)rA2)[q4];
            sA2[2*q4] = mkv2(qc.x, qc.y); sA2[2*q4+1] = mkv2(qc.z, qc.w);
        }
        const float* baseB = Whh1 + (size_t)e * G3 * NH;
        const float* rB0 = baseB + (size_t)j * NH + k0h;
        const float* rB1 = baseB + (size_t)(j + 32) * NH + k0h;
        const float* rB2 = baseB + (size_t)(j + 64) * NH + k0h;
        #pragma unroll
        for (int q4 = 0; q4 < 4; q4++) {
            float4 qa = ((const float4*)rB0)[q4];
            wB0[2*q4] = mkv2(qa.x, qa.y); wB0[2*q4+1] = mkv2(qa.z, qa.w);
            float4 qb = ((const float4*)rB1)[q4];
            wB1[2*q4] = mkv2(qb.x, qb.y); wB1[2*q4+1] = mkv2(qb.z, qb.w);
            float4 qc = ((const float4*)rB2)[q4];
            wB2[2*q4] = mkv2(qc.x, qc.y); wB2[2*q4+1] = mkv2(qc.z, qc.w);
        }
    }
    const float selb0 = hlf ? bih1[e*G3 + j]      : bhh0[e*G3 + j];
    const float selb1 = hlf ? bih1[e*G3 + j + 32] : bhh0[e*G3 + j + 32];
    const float selb2 = hlf ? bih1[e*G3 + j + 64] : bhh0[e*G3 + j + 64];
    const float whb0  = hlf ? 0.f : bhh1[e*G3 + j];
    const float whb1  = hlf ? 0.f : bhh1[e*G3 + j + 32];
    const float whb2  = hlf ? 0.f : bhh1[e*G3 + j + 64];

    // dreg = bih0 + Wih0 @ (b_in + h_embed), added once (half0 side of reduce)
    float dreg0, dreg1, dreg2;
    {
        float s0 = bih0[e*G3 + j], s1 = bih0[e*G3 + j + 32], s2 = bih0[e*G3 + j + 64];
        const float* w0 = Wih0 + ((size_t)e * G3 + j) * ND;
        const float* w1 = Wih0 + ((size_t)e * G3 + j + 32) * ND;
        const float* w2 = Wih0 + ((size_t)e * G3 + j + 64) * ND;
        for (int d = 0; d < ND; d++) {
            float bb = bbL[d];
            s0 += w0[d] * bb; s1 += w1[d] * bb; s2 += w2[d] * bb;
        }
        dreg0 = hlf ? 0.f : s0;
        dreg1 = hlf ? 0.f : s1;
        dreg2 = hlf ? 0.f : s2;
    }

    // ---- pipeline state ----
    v2f h0v[16], h1v[8];
    #pragma unroll
    for (int k = 0; k < 16; k++) h0v[k] = splat2(0.f);
    #pragma unroll
    for (int k = 0; k < 8; k++)  h1v[k] = splat2(0.f);
    float hold = 0.f;                    // half0: h0_j ; half1: h1_j (skewed)
    float lmul = hlf ? 0.f : 1.f;        // neutralizes the fake first L1 step
    float* hptr = (hlf ? h1L : h0L) + j;

    const float* xg = x + (size_t)b * LSEQ * NF;
    const float4* CT4 = (const float4*)CT;

    for (int ch = 0; ch < NCHUNK; ch++) {
        // stage x chunk (contiguous float4 global loads), transpose to [f][t]
        {
            const float4* xc4 = (const float4*)(xg + (size_t)ch * CHUNK * NF);
            for (int i4 = tid; i4 < (CHUNK * NF) / 4; i4 += 64) {
                float4 v = xc4[i4];
                int idx = i4 * 4;
                #pragma unroll
                for (int u = 0; u < 4; u++) {
                    int id = idx + u;
                    int it = (int)(((unsigned)id * 5243u) >> 18);   // id/50
                    int f  = id - it * 50;
                    float val = (u == 0) ? v.x : (u == 1) ? v.y : (u == 2) ? v.z : v.w;
                    xs[f * CHUNK + it] = val;
                }
            }
        }

        for (int blk = 0; blk < NBLK; blk++) {
            const int ib0 = blk * TBLK;
            // ---- xg0 partials for TBLK steps (f-split across halves) ----
            v2f a0[4], a1[4], a2[4];
            #pragma unroll
            for (int p = 0; p < 4; p++) {
                a0[p] = splat2(dreg0); a1[p] = splat2(dreg1); a2[p] = splat2(dreg2);
            }
            {
                const int fb = 25 * hlf;
                #pragma unroll 5
                for (int f = 0; f < 25; f++) {
                    const int fg = fb + f;
                    float4 cw = CT4[fg * 32 + j];            // rows j, j+32, j+64
                    const float4* xp = (const float4*)(xs + fg * CHUNK + ib0);
                    float4 xa = xp[0], xb = xp[1];
                    v2f xv[4] = { mkv2(xa.x, xa.y), mkv2(xa.z, xa.w),
                                  mkv2(xb.x, xb.y), mkv2(xb.z, xb.w) };
                    v2f w0 = splat2(cw.x), w1 = splat2(cw.y), w2 = splat2(cw.z);
                    #pragma unroll
                    for (int p = 0; p < 4; p++) {
                        a0[p] = v2fma(w0, xv[p], a0[p]);
                        a1[p] = v2fma(w1, xv[p], a1[p]);
                        a2[p] = v2fma(w2, xv[p], a2[p]);
                    }
                }
            }
            // cross-half reduce of xg0 (off the per-step chain)
            #pragma unroll
            for (int p = 0; p < 4; p++) {
                a0[p].x += __shfl_xor(a0[p].x, 32, 64); a0[p].y += __shfl_xor(a0[p].y, 32, 64);
                a1[p].x += __shfl_xor(a1[p].x, 32, 64); a1[p].y += __shfl_xor(a1[p].y, 32, 64);
                a2[p].x += __shfl_xor(a2[p].x, 32, 64); a2[p].y += __shfl_xor(a2[p].y, 32, 64);
            }

            // ---- TBLK pipelined steps: L0(t) on half0 || L1(t-1) on half1 ----
            #pragma unroll
            for (int i = 0; i < TBLK; i++) {
                // B-dots FIRST (k-half over h1), then start the swizzle reduce
                v2f dB0 = mkv2(whb0, 0.f), dB1 = mkv2(whb1, 0.f), dB2 = mkv2(whb2, 0.f);
                #pragma unroll
                for (int k = 0; k < 8; k++) {
                    dB0 = v2fma(wB0[k], h1v[k], dB0);
                    dB1 = v2fma(wB1[k], h1v[k], dB1);
                    dB2 = v2fma(wB2[k], h1v[k], dB2);
                }
                float B0 = dB0.x + dB0.y, B1 = dB1.x + dB1.y, B2 = dB2.x + dB2.y;
                float R0 = B0 + __shfl_xor(B0, 32, 64);   // swizzle latency is
                float R1 = B1 + __shfl_xor(B1, 32, 64);   // covered by A-dots
                float R2 = B2 + __shfl_xor(B2, 32, 64);
                // A-dots: full dots over h0 (half0: Whh0; half1: Wih1)
                v2f dA0 = mkv2(selb0, 0.f), dA1 = mkv2(selb1, 0.f), dA2 = mkv2(selb2, 0.f);
                #pragma unroll
                for (int k = 0; k < 16; k++) {
                    dA0 = v2fma(sA0[k], h0v[k], dA0);
                    dA1 = v2fma(sA1[k], h0v[k], dA1);
                    dA2 = v2fma(sA2[k], h0v[k], dA2);
                }
                float A0 = dA0.x + dA0.y, A1 = dA1.x + dA1.y, A2 = dA2.x + dA2.y;
                const float ac0 = a0[i >> 1][i & 1];
                const float ac1 = a1[i >> 1][i & 1];
                const float ac2 = a2[i >> 1][i & 1];
                // gate assembly (uniform instructions, per-half operand select)
                float o0   = hlf ? R0 : ac0;
                float o1   = hlf ? R1 : ac1;
                float npre = hlf ? A2 : ac2;
                float gn   = hlf ? R2 : A2;
                float r = fsig(A0 + o0);
                float z = fsig(A1 + o1);
                float n = ftanh(npre + r * gn);
                float hnew = (n + z * (hold - n)) * lmul;
                hold = hnew;
                lmul = 1.f;
                hptr[0] = hnew;                       // one ds_write covers h0 & h1
                // read-back: h1 first (next step's B-dots need it first)
                const float4* h1q = (const float4*)(h1L + k0h);
                #pragma unroll
                for (int q4 = 0; q4 < 4; q4++) {
                    float4 qq = h1q[q4];
                    h1v[2*q4]   = mkv2(qq.x, qq.y);
                    h1v[2*q4+1] = mkv2(qq.z, qq.w);
                }
                const float4* h0q = (const float4*)h0L;
                #pragma unroll
                for (int q4 = 0; q4 < 8; q4++) {
                    float4 qq = h0q[q4];
                    h0v[2*q4]   = mkv2(qq.x, qq.y);
                    h0v[2*q4+1] = mkv2(qq.z, qq.w);
                }
            }
        }
    }

    // ---- epilogue: L1(LSEQ-1) (results used from half1 only) ----
    {
        v2f dA0 = mkv2(selb0, 0.f), dA1 = mkv2(selb1, 0.f), dA2 = mkv2(selb2, 0.f);
        #pragma unroll
        for (int k = 0; k < 16; k++) {
            dA0 = v2fma(sA0[k], h0v[k], dA0);
            dA1 = v2fma(sA1[k], h0v[k], dA1);
            dA2 = v2fma(sA2[k], h0v[k], dA2);
        }
        v2f dB0 = mkv2(whb0, 0.f), dB1 = mkv2(whb1, 0.f), dB2 = mkv2(whb2, 0.f);
        #pragma unroll
        for (int k = 0; k < 8; k++) {
            dB0 = v2fma(wB0[k], h1v[k], dB0);
            dB1 = v2fma(wB1[k], h1v[k], dB1);
            dB2 = v2fma(wB2[k], h1v[k], dB2);
        }
        float A0 = dA0.x + dA0.y, A1 = dA1.x + dA1.y, A2 = dA2.x + dA2.y;
        float B0 = dB0.x + dB0.y, B1 = dB1.x + dB1.y, B2 = dB2.x + dB2.y;
        float R0 = B0 + __shfl_xor(B0, 32, 64);
        float R1 = B1 + __shfl_xor(B1, 32, 64);
        float R2 = B2 + __shfl_xor(B2, 32, 64);
        float r = fsig(A0 + R0);
        float z = fsig(A1 + R1);
        float n = ftanh(A2 + r * R2);
        float hfin = n + z * (hold - n);
        if (hlf) h1L[j] = hfin;
    }

    // ---- head MLP + weighted accumulation ----
    if (tid < 32) {
        float s = bh1[e * NHU + tid];
        const float* wr = Wh1 + ((size_t)e * NHU + tid) * NH;
        #pragma unroll
        for (int d = 0; d < NH; d++) s += wr[d] * h1L[d];
        float hid = fmaxf(s, 0.f);
        float c = hid * Wh2[e * NHU + tid];
        #pragma unroll
        for (int off = 16; off > 0; off >>= 1) c += __shfl_down(c, off, 64);
        if (tid == 0) atomicAdd(out + b, wgt * (c + bh2[e]));
    }
}

extern "C" void kernel_launch(void* const* d_in, const int* in_sizes, int n_in,
                              void* d_out, int out_size, void* d_ws, size_t ws_size,
                              hipStream_t stream) {
    const float* x       = (const float*)d_in[0];
    const int*   horizon = (const int*)  d_in[1];
    const float* W_in    = (const float*)d_in[2];
    const float* b_in    = (const float*)d_in[3];
    const float* emb     = (const float*)d_in[4];
    const float* W_gate  = (const float*)d_in[5];
    const float* b_gate  = (const float*)d_in[6];
    const float* Wih0    = (const float*)d_in[7];
    const float* Whh0    = (const float*)d_in[8];
    const float* bih0    = (const float*)d_in[9];
    const float* bhh0    = (const float*)d_in[10];
    const float* Wih1    = (const float*)d_in[11];
    const float* Whh1    = (const float*)d_in[12];
    const float* bih1    = (const float*)d_in[13];
    const float* bhh1    = (const float*)d_in[14];
    const float* Wh1     = (const float*)d_in[15];
    const float* bh1     = (const float*)d_in[16];
    const float* Wh2     = (const float*)d_in[17];
    const float* bh2     = (const float*)d_in[18];
    float* out = (float*)d_out;
    float* Cg  = (float*)d_ws;   // NE*NF*32*4 floats = 102.4 KB

    hipMemsetAsync(d_out, 0, NB * sizeof(float), stream);
    compute_C_kernel<<<dim3(NE), dim3(256), 0, stream>>>(Wih0, W_in, Cg);
    moe_gru_kernel<<<dim3(NB * NE), dim3(64), 0, stream>>>(
        x, horizon, emb, W_gate, b_gate, b_in,
        Wih0, Whh0, bih0, bhh0, Wih1, Whh1, bih1, bhh1,
        Wh1, bh1, Wh2, bh2, Cg, out);
}

// Round 7
// 1336.383 us; speedup vs baseline: 1.7560x; 1.0547x over previous
//
#include <hip/hip_runtime.h>
#include <math.h>

#define NB   256
#define LSEQ 1800
#define NF   50
#define NE   4
#define NH   32
#define G3   96
#define ND   64
#define NHU  32
#define CHUNK 72
#define TBLK  8
#define NCHUNK (LSEQ / CHUNK)   // 25
#define NBLK   (CHUNK / TBLK)   // 9

typedef float v2f __attribute__((ext_vector_type(2)));

__device__ __forceinline__ v2f v2fma(v2f a, v2f b, v2f c) {
    return __builtin_elementwise_fma(a, b, c);
}
__device__ __forceinline__ v2f mkv2(float a, float b) { v2f t; t.x = a; t.y = b; return t; }
__device__ __forceinline__ v2f splat2(float s) { v2f t; t.x = s; t.y = s; return t; }

// ---------------------------------------------------------------------------
// Kernel 1: fold input projection into layer-0 input weights.
// Cg[e][f][g] = sum_d Wih0[e][g][d] * W_in[d][f]   (scalar [f][96] layout:
// b32 reads at bank j -> conflict-free)
// ---------------------------------------------------------------------------
__global__ void compute_C_kernel(const float* __restrict__ Wih0,
                                 const float* __restrict__ W_in,
                                 float* __restrict__ Cg) {
    int e = blockIdx.x;
    for (int idx = threadIdx.x; idx < NF * G3; idx += blockDim.x) {
        int f = idx / G3;
        int g = idx - f * G3;
        const float* wr = Wih0 + ((size_t)e * G3 + g) * ND;
        float s = 0.f;
        #pragma unroll 8
        for (int d = 0; d < ND; d++) s += wr[d] * W_in[d * NF + f];
        Cg[(size_t)e * NF * G3 + idx] = s;
    }
}

// Fast transcendentals on v_exp_f32 / v_rcp_f32.
__device__ __forceinline__ float fsig(float x) {
    float e = __builtin_amdgcn_exp2f(-1.442695041f * x);
    return __builtin_amdgcn_rcpf(1.f + e);
}
__device__ __forceinline__ float ftanh(float x) {
    x = fmaxf(x, -20.f);
    float e = __builtin_amdgcn_exp2f(-2.885390082f * x);
    return (1.f - e) * __builtin_amdgcn_rcpf(1.f + e);
}

// ---------------------------------------------------------------------------
// One 64-thread (single-wave) block per (batch, expert); unrouted blocks exit.
// Role split with 1-step skew: half0 lane j = L0(t) row j (full 32-dots over
// h0); half1 lane j = L1(t-1) row j (xg1 full dots over h0 + gh1 k-half dots
// over h1, one xor32 reduce). h0 broadcast via v_readlane (VALU-only, no DS
// latency); h1 exchanged through LDS with its round trip covered by the
// transport + A-dots. No barriers (single wave).
// ---------------------------------------------------------------------------
__global__ __launch_bounds__(64, 1)
void moe_gru_kernel(const float* __restrict__ x,
                    const int*   __restrict__ horizon,
                    const float* __restrict__ emb,
                    const float* __restrict__ W_gate,
                    const float* __restrict__ b_gate,
                    const float* __restrict__ b_in,
                    const float* __restrict__ Wih0,
                    const float* __restrict__ Whh0,
                    const float* __restrict__ bih0,
                    const float* __restrict__ bhh0,
                    const float* __restrict__ Wih1,
                    const float* __restrict__ Whh1,
                    const float* __restrict__ bih1,
                    const float* __restrict__ bhh1,
                    const float* __restrict__ Wh1,
                    const float* __restrict__ bh1,
                    const float* __restrict__ Wh2,
                    const float* __restrict__ bh2,
                    const float* __restrict__ Cg,
                    float* __restrict__ out) {
    __shared__ __align__(16) float smem[4800 + 3600 + 64 + 64 + 32];
    float* CT  = smem;                  // [f][96] folded xg0 weights
    float* xs  = smem + 4800;           // [f][CHUNK] transposed x chunk
    float* heL = smem + 4800 + 3600;    // 64: h_embed
    float* bbL = heL + 64;              // 64: b_in + h_embed
    float* h1L = bbL + 64;              // 32: h1 exchange + final h1 for head

    const int bid = blockIdx.x;
    const int b   = bid >> 2;
    const int e   = bid & 3;
    const int tid = threadIdx.x;
    const int j   = tid & 31;
    const int hlf = tid >> 5;
    const int k0h = hlf << 4;

    // ---- stage h_embed / (b_in + h_embed) (wave-synchronous) ----
    {
        int hor = horizon[b];
        float he = emb[(size_t)hor * ND + tid];
        heL[tid] = he;
        bbL[tid] = he + b_in[tid];
    }

    // ---- gating (every thread computes identically) ----
    float lg[NE];
    #pragma unroll
    for (int q = 0; q < NE; q++) {
        float s = b_gate[q];
        for (int d = 0; d < ND; d++) s += heL[d] * W_gate[q * ND + d];
        lg[q] = s;
    }
    int i1 = 0;
    #pragma unroll
    for (int q = 1; q < NE; q++) if (lg[q] > lg[i1]) i1 = q;
    int i2 = (i1 == 0) ? 1 : 0;
    #pragma unroll
    for (int q = 0; q < NE; q++) if (q != i1 && lg[q] > lg[i2]) i2 = q;
    if (e != i1 && e != i2) return;          // block-uniform
    const float ex2 = expf(lg[i2] - lg[i1]);
    const float wgt = (e == i1) ? (1.f / (1.f + ex2)) : (ex2 / (1.f + ex2));

    // ---- stage folded xg0 weights into LDS ----
    for (int idx = tid; idx < NF * G3; idx += 64)
        CT[idx] = Cg[(size_t)e * NF * G3 + idx];

    // ---- per-lane weights ----
    // selA: half0 -> Whh0 rows {j, j+32, j+64}; half1 -> Wih1 rows (full 32-k)
    v2f sA0[16], sA1[16], sA2[16];
    // wB: Whh1 rows {j, j+32, j+64}, k-half [k0h, k0h+16)
    v2f wB0[8], wB1[8], wB2[8];
    {
        const float* baseA = (hlf ? Wih1 : Whh0) + (size_t)e * G3 * NH;
        const float* rA0 = baseA + (size_t)j * NH;
        const float* rA1 = baseA + (size_t)(j + 32) * NH;
        const float* rA2 = baseA + (size_t)(j + 64) * NH;
        #pragma unroll
        for (int q4 = 0; q4 < 8; q4++) {
            float4 qa = ((const float4*)rA0)[q4];
            sA0[2*q4] = mkv2(qa.x, qa.y); sA0[2*q4+1] = mkv2(qa.z, qa.w);
            float4 qb = ((const float4*)rA1)[q4];
            sA1[2*q4] = mkv2(qb.x, qb.y); sA1[2*q4+1] = mkv2(qb.z, qb.w);
            float4 qc = ((const float4*)rA2)[q4];
            sA2[2*q4] = mkv2(qc.x, qc.y); sA2[2*q4+1] = mkv2(qc.z, qc.w);
        }
        const float* baseB = Whh1 + (size_t)e * G3 * NH;
        const float* rB0 = baseB + (size_t)j * NH + k0h;
        const float* rB1 = baseB + (size_t)(j + 32) * NH + k0h;
        const float* rB2 = baseB + (size_t)(j + 64) * NH + k0h;
        #pragma unroll
        for (int q4 = 0; q4 < 4; q4++) {
            float4 qa = ((const float4*)rB0)[q4];
            wB0[2*q4] = mkv2(qa.x, qa.y); wB0[2*q4+1] = mkv2(qa.z, qa.w);
            float4 qb = ((const float4*)rB1)[q4];
            wB1[2*q4] = mkv2(qb.x, qb.y); wB1[2*q4+1] = mkv2(qb.z, qb.w);
            float4 qc = ((const float4*)rB2)[q4];
            wB2[2*q4] = mkv2(qc.x, qc.y); wB2[2*q4+1] = mkv2(qc.z, qc.w);
        }
    }
    const float selb0 = hlf ? bih1[e*G3 + j]      : bhh0[e*G3 + j];
    const float selb1 = hlf ? bih1[e*G3 + j + 32] : bhh0[e*G3 + j + 32];
    const float selb2 = hlf ? bih1[e*G3 + j + 64] : bhh0[e*G3 + j + 64];
    const float whb0  = hlf ? 0.f : bhh1[e*G3 + j];
    const float whb1  = hlf ? 0.f : bhh1[e*G3 + j + 32];
    const float whb2  = hlf ? 0.f : bhh1[e*G3 + j + 64];

    // dreg = bih0 + Wih0 @ (b_in + h_embed), added once (half0 side of reduce)
    float dreg0, dreg1, dreg2;
    {
        float s0 = bih0[e*G3 + j], s1 = bih0[e*G3 + j + 32], s2 = bih0[e*G3 + j + 64];
        const float* w0 = Wih0 + ((size_t)e * G3 + j) * ND;
        const float* w1 = Wih0 + ((size_t)e * G3 + j + 32) * ND;
        const float* w2 = Wih0 + ((size_t)e * G3 + j + 64) * ND;
        for (int d = 0; d < ND; d++) {
            float bb = bbL[d];
            s0 += w0[d] * bb; s1 += w1[d] * bb; s2 += w2[d] * bb;
        }
        dreg0 = hlf ? 0.f : s0;
        dreg1 = hlf ? 0.f : s1;
        dreg2 = hlf ? 0.f : s2;
    }

    // ---- pipeline state ----
    v2f h0v[16], h1v[8];
    #pragma unroll
    for (int k = 0; k < 16; k++) h0v[k] = splat2(0.f);
    #pragma unroll
    for (int k = 0; k < 8; k++)  h1v[k] = splat2(0.f);
    float hold = 0.f;                    // half0: h0_j ; half1: h1_j (skewed)
    float lmul = hlf ? 0.f : 1.f;        // neutralizes the fake first L1 step
    if (tid < 32) h1L[tid] = 0.f;

    const float* xg = x + (size_t)b * LSEQ * NF;

    for (int ch = 0; ch < NCHUNK; ch++) {
        // stage x chunk (contiguous float4 global loads), transpose to [f][t]
        {
            const float4* xc4 = (const float4*)(xg + (size_t)ch * CHUNK * NF);
            for (int i4 = tid; i4 < (CHUNK * NF) / 4; i4 += 64) {
                float4 v = xc4[i4];
                int idx = i4 * 4;
                #pragma unroll
                for (int u = 0; u < 4; u++) {
                    int id = idx + u;
                    int it = (int)(((unsigned)id * 5243u) >> 18);   // id/50
                    int f  = id - it * 50;
                    float val = (u == 0) ? v.x : (u == 1) ? v.y : (u == 2) ? v.z : v.w;
                    xs[f * CHUNK + it] = val;
                }
            }
        }

        for (int blk = 0; blk < NBLK; blk++) {
            const int ib0 = blk * TBLK;
            // ---- xg0 partials for TBLK steps (f-split across halves) ----
            v2f a0[4], a1[4], a2[4];
            #pragma unroll
            for (int p = 0; p < 4; p++) {
                a0[p] = splat2(dreg0); a1[p] = splat2(dreg1); a2[p] = splat2(dreg2);
            }
            {
                const int fb = 25 * hlf;
                #pragma unroll 5
                for (int f = 0; f < 25; f++) {
                    const int fg = fb + f;
                    float c0 = CT[fg * G3 + j];
                    float c1 = CT[fg * G3 + j + 32];
                    float c2 = CT[fg * G3 + j + 64];
                    const float4* xp = (const float4*)(xs + fg * CHUNK + ib0);
                    float4 xa = xp[0], xb = xp[1];
                    v2f xv[4] = { mkv2(xa.x, xa.y), mkv2(xa.z, xa.w),
                                  mkv2(xb.x, xb.y), mkv2(xb.z, xb.w) };
                    v2f w0 = splat2(c0), w1 = splat2(c1), w2 = splat2(c2);
                    #pragma unroll
                    for (int p = 0; p < 4; p++) {
                        a0[p] = v2fma(w0, xv[p], a0[p]);
                        a1[p] = v2fma(w1, xv[p], a1[p]);
                        a2[p] = v2fma(w2, xv[p], a2[p]);
                    }
                }
            }
            // cross-half reduce of xg0 (off the per-step chain)
            #pragma unroll
            for (int p = 0; p < 4; p++) {
                a0[p].x += __shfl_xor(a0[p].x, 32, 64); a0[p].y += __shfl_xor(a0[p].y, 32, 64);
                a1[p].x += __shfl_xor(a1[p].x, 32, 64); a1[p].y += __shfl_xor(a1[p].y, 32, 64);
                a2[p].x += __shfl_xor(a2[p].x, 32, 64); a2[p].y += __shfl_xor(a2[p].y, 32, 64);
            }

            // ---- TBLK pipelined steps: L0(t) on half0 || L1(t-1) on half1 ----
            #pragma unroll
            for (int i = 0; i < TBLK; i++) {
                // B-dots (k-half over h1 from LDS), start the xor32 reduce
                v2f dB0 = mkv2(whb0, 0.f), dB1 = mkv2(whb1, 0.f), dB2 = mkv2(whb2, 0.f);
                #pragma unroll
                for (int k = 0; k < 8; k++) {
                    dB0 = v2fma(wB0[k], h1v[k], dB0);
                    dB1 = v2fma(wB1[k], h1v[k], dB1);
                    dB2 = v2fma(wB2[k], h1v[k], dB2);
                }
                float B0 = dB0.x + dB0.y, B1 = dB1.x + dB1.y, B2 = dB2.x + dB2.y;
                float R0 = B0 + __shfl_xor(B0, 32, 64);   // covered by A-dots
                float R1 = B1 + __shfl_xor(B1, 32, 64);
                float R2 = B2 + __shfl_xor(B2, 32, 64);
                // A-dots: full dots over transported h0
                v2f dA0 = mkv2(selb0, 0.f), dA1 = mkv2(selb1, 0.f), dA2 = mkv2(selb2, 0.f);
                #pragma unroll
                for (int k = 0; k < 16; k++) {
                    dA0 = v2fma(sA0[k], h0v[k], dA0);
                    dA1 = v2fma(sA1[k], h0v[k], dA1);
                    dA2 = v2fma(sA2[k], h0v[k], dA2);
                }
                float A0 = dA0.x + dA0.y, A1 = dA1.x + dA1.y, A2 = dA2.x + dA2.y;
                const float ac0 = a0[i >> 1][i & 1];
                const float ac1 = a1[i >> 1][i & 1];
                const float ac2 = a2[i >> 1][i & 1];
                // gate assembly (uniform instructions, per-half operand select)
                float o0   = hlf ? R0 : ac0;
                float o1   = hlf ? R1 : ac1;
                float npre = hlf ? A2 : ac2;
                float gn   = hlf ? R2 : A2;
                float r = fsig(A0 + o0);
                float z = fsig(A1 + o1);
                float n = ftanh(npre + r * gn);
                float hnew = (n + z * (hold - n)) * lmul;
                hold = hnew;
                lmul = 1.f;
                // h1 exchange via LDS (round trip covered by transport + A-dots)
                if (hlf) h1L[j] = hnew;
                const float4* h1q = (const float4*)(h1L + k0h);
                float4 q0 = h1q[0], q1 = h1q[1], q2 = h1q[2], q3 = h1q[3];
                h1v[0] = mkv2(q0.x, q0.y); h1v[1] = mkv2(q0.z, q0.w);
                h1v[2] = mkv2(q1.x, q1.y); h1v[3] = mkv2(q1.z, q1.w);
                h1v[4] = mkv2(q2.x, q2.y); h1v[5] = mkv2(q2.z, q2.w);
                h1v[6] = mkv2(q3.x, q3.y); h1v[7] = mkv2(q3.z, q3.w);
                // h0 broadcast via v_readlane: VALU-only, no DS latency
                {
                    int hni = __float_as_int(hnew);
                    #pragma unroll
                    for (int k = 0; k < 16; k++) {
                        float e0 = __int_as_float(__builtin_amdgcn_readlane(hni, 2*k));
                        float e1 = __int_as_float(__builtin_amdgcn_readlane(hni, 2*k+1));
                        h0v[k] = mkv2(e0, e1);
                    }
                }
            }
        }
    }

    // ---- epilogue: L1(LSEQ-1) (results used from half1 only) ----
    {
        v2f dA0 = mkv2(selb0, 0.f), dA1 = mkv2(selb1, 0.f), dA2 = mkv2(selb2, 0.f);
        #pragma unroll
        for (int k = 0; k < 16; k++) {
            dA0 = v2fma(sA0[k], h0v[k], dA0);
            dA1 = v2fma(sA1[k], h0v[k], dA1);
            dA2 = v2fma(sA2[k], h0v[k], dA2);
        }
        v2f dB0 = mkv2(whb0, 0.f), dB1 = mkv2(whb1, 0.f), dB2 = mkv2(whb2, 0.f);
        #pragma unroll
        for (int k = 0; k < 8; k++) {
            dB0 = v2fma(wB0[k], h1v[k], dB0);
            dB1 = v2fma(wB1[k], h1v[k], dB1);
            dB2 = v2fma(wB2[k], h1v[k], dB2);
        }
        float A0 = dA0.x + dA0.y, A1 = dA1.x + dA1.y, A2 = dA2.x + dA2.y;
        float B0 = dB0.x + dB0.y, B1 = dB1.x + dB1.y, B2 = dB2.x + dB2.y;
        float R0 = B0 + __shfl_xor(B0, 32, 64);
        float R1 = B1 + __shfl_xor(B1, 32, 64);
        float R2 = B2 + __shfl_xor(B2, 32, 64);
        float r = fsig(A0 + R0);
        float z = fsig(A1 + R1);
        float n = ftanh(A2 + r * R2);
        float hfin = n + z * (hold - n);
        if (hlf) h1L[j] = hfin;
    }

    // ---- head MLP + weighted accumulation ----
    if (tid < 32) {
        float s = bh1[e * NHU + tid];
        const float* wr = Wh1 + ((size_t)e * NHU + tid) * NH;
        #pragma unroll
        for (int d = 0; d < NH; d++) s += wr[d] * h1L[d];
        float hid = fmaxf(s, 0.f);
        float c = hid * Wh2[e * NHU + tid];
        #pragma unroll
        for (int off = 16; off > 0; off >>= 1) c += __shfl_down(c, off, 64);
        if (tid == 0) atomicAdd(out + b, wgt * (c + bh2[e]));
    }
}

extern "C" void kernel_launch(void* const* d_in, const int* in_sizes, int n_in,
                              void* d_out, int out_size, void* d_ws, size_t ws_size,
                              hipStream_t stream) {
    const float* x       = (const float*)d_in[0];
    const int*   horizon = (const int*)  d_in[1];
    const float* W_in    = (const float*)d_in[2];
    const float* b_in    = (const float*)d_in[3];
    const float* emb     = (const float*)d_in[4];
    const float* W_gate  = (const float*)d_in[5];
    const float* b_gate  = (const float*)d_in[6];
    const float* Wih0    = (const float*)d_in[7];
    const float* Whh0    = (const float*)d_in[8];
    const float* bih0    = (const float*)d_in[9];
    const float* bhh0    = (const float*)d_in[10];
    const float* Wih1    = (const float*)d_in[11];
    const float* Whh1    = (const float*)d_in[12];
    const float* bih1    = (const float*)d_in[13];
    const float* bhh1    = (const float*)d_in[14];
    const float* Wh1     = (const float*)d_in[15];
    const float* bh1     = (const float*)d_in[16];
    const float* Wh2     = (const float*)d_in[17];
    const float* bh2     = (const float*)d_in[18];
    float* out = (float*)d_out;
    float* Cg  = (float*)d_ws;   // NE*NF*G3 floats = 76.8 KB

    hipMemsetAsync(d_out, 0, NB * sizeof(float), stream);
    compute_C_kernel<<<dim3(NE), dim3(256), 0, stream>>>(Wih0, W_in, Cg);
    moe_gru_kernel<<<dim3(NB * NE), dim3(64), 0, stream>>>(
        x, horizon, emb, W_gate, b_gate, b_in,
        Wih0, Whh0, bih0, bhh0, Wih1, Whh1, bih1, bhh1,
        Wh1, bh1, Wh2, bh2, Cg, out);
}